// Round 1
// baseline (948.213 us; speedup 1.0000x reference)
//
#include <hip/hip_runtime.h>
#include <math.h>

static constexpr int N_NODES = 100000;
static constexpr int N_EDGES = 3200000;
static constexpr int F_INC   = 256;
static constexpr int HIDC    = 16;
static constexpr int NCLS    = 32;

__global__ void k_init_deg(float* deg) {
    int i = blockIdx.x * blockDim.x + threadIdx.x;
    if (i < N_NODES) deg[i] = 1.0f;
}

__global__ void k_count_deg(const int* __restrict__ dst, float* deg) {
    int e = blockIdx.x * blockDim.x + threadIdx.x;
    if (e < N_EDGES) atomicAdd(&deg[dst[e]], 1.0f);
}

__global__ void k_rsqrt(float* deg) {
    int i = blockIdx.x * blockDim.x + threadIdx.x;
    if (i < N_NODES) deg[i] = rsqrtf(deg[i]);
}

__global__ void k_norm(const int* __restrict__ src, const int* __restrict__ dst,
                       const float* __restrict__ dis, float* __restrict__ nrm) {
    int e = blockIdx.x * blockDim.x + threadIdx.x;
    if (e < N_EDGES) nrm[e] = dis[src[e]] * dis[dst[e]];
}

__global__ __launch_bounds__(256) void k_linear1(const float* __restrict__ x,
                                                 const float* __restrict__ W1,
                                                 float* __restrict__ h) {
    __shared__ float Ws[F_INC * HIDC];
    for (int i = threadIdx.x; i < F_INC * HIDC; i += 256) Ws[i] = W1[i];
    __syncthreads();
    int n = blockIdx.x * blockDim.x + threadIdx.x;
    if (n >= N_NODES) return;
    float acc[HIDC];
    #pragma unroll
    for (int j = 0; j < HIDC; ++j) acc[j] = 0.f;
    const float4* xr = (const float4*)(x + (size_t)n * F_INC);
    for (int k4 = 0; k4 < F_INC / 4; ++k4) {
        float4 v = xr[k4];
        const float* w = &Ws[k4 * 4 * HIDC];
        #pragma unroll
        for (int j = 0; j < HIDC; ++j)
            acc[j] += v.x * w[j] + v.y * w[HIDC + j] + v.z * w[2 * HIDC + j] + v.w * w[3 * HIDC + j];
    }
    float4* o = (float4*)(h + (size_t)n * HIDC);
    #pragma unroll
    for (int j4 = 0; j4 < HIDC / 4; ++j4)
        o[j4] = make_float4(acc[4 * j4], acc[4 * j4 + 1], acc[4 * j4 + 2], acc[4 * j4 + 3]);
}

template<int D>
__global__ void k_init_agg(const float* __restrict__ h, const float* __restrict__ dis,
                           float* __restrict__ agg) {
    int idx = blockIdx.x * blockDim.x + threadIdx.x;
    if (idx < N_NODES * D) {
        int n = idx / D;
        float s = dis[n];
        agg[idx] = s * s * h[idx];
    }
}

template<int D>
__global__ void k_scatter(const int* __restrict__ src, const int* __restrict__ dst,
                          const float* __restrict__ nrm, const float* __restrict__ h,
                          float* agg) {
    int idx = blockIdx.x * blockDim.x + threadIdx.x;
    if (idx >= N_EDGES * D) return;
    int e = idx / D;
    int d = idx - e * D;
    int s = src[e];
    int t = dst[e];
    float v = h[(size_t)s * D + d] * nrm[e];
    atomicAdd(&agg[(size_t)t * D + d], v);
}

template<int DIN, int DOUT>
__global__ __launch_bounds__(256) void k_finlin(const float* __restrict__ agg,
                                                const float* __restrict__ bias,
                                                const float* __restrict__ W,
                                                float* __restrict__ hout) {
    __shared__ float Ws[DIN * DOUT];
    __shared__ float bs[DIN];
    for (int i = threadIdx.x; i < DIN * DOUT; i += 256) Ws[i] = W[i];
    if (threadIdx.x < DIN) bs[threadIdx.x] = bias[threadIdx.x];
    __syncthreads();
    int n = blockIdx.x * blockDim.x + threadIdx.x;
    if (n >= N_NODES) return;
    float act[DIN];
    const float4* ar = (const float4*)(agg + (size_t)n * DIN);
    #pragma unroll
    for (int k4 = 0; k4 < DIN / 4; ++k4) {
        float4 v = ar[k4];
        float t0 = v.x + bs[4 * k4 + 0]; act[4 * k4 + 0] = t0 > 0.f ? t0 : expm1f(t0);
        float t1 = v.y + bs[4 * k4 + 1]; act[4 * k4 + 1] = t1 > 0.f ? t1 : expm1f(t1);
        float t2 = v.z + bs[4 * k4 + 2]; act[4 * k4 + 2] = t2 > 0.f ? t2 : expm1f(t2);
        float t3 = v.w + bs[4 * k4 + 3]; act[4 * k4 + 3] = t3 > 0.f ? t3 : expm1f(t3);
    }
    float acc[DOUT];
    #pragma unroll
    for (int j = 0; j < DOUT; ++j) acc[j] = 0.f;
    for (int k = 0; k < DIN; ++k) {
        float a = act[k];
        #pragma unroll
        for (int j = 0; j < DOUT; ++j) acc[j] += a * Ws[k * DOUT + j];
    }
    float4* o = (float4*)(hout + (size_t)n * DOUT);
    #pragma unroll
    for (int j4 = 0; j4 < DOUT / 4; ++j4)
        o[j4] = make_float4(acc[4 * j4], acc[4 * j4 + 1], acc[4 * j4 + 2], acc[4 * j4 + 3]);
}

__global__ __launch_bounds__(256) void k_final(const float* __restrict__ agg,
                                               const float* __restrict__ bias,
                                               float* __restrict__ out) {
    __shared__ float bs[NCLS];
    if (threadIdx.x < NCLS) bs[threadIdx.x] = bias[threadIdx.x];
    __syncthreads();
    int n = blockIdx.x * blockDim.x + threadIdx.x;
    if (n >= N_NODES) return;
    float r[NCLS];
    const float4* ar = (const float4*)(agg + (size_t)n * NCLS);
    #pragma unroll
    for (int k4 = 0; k4 < NCLS / 4; ++k4) {
        float4 v = ar[k4];
        float t0 = v.x + bs[4 * k4 + 0]; r[4 * k4 + 0] = t0 > 0.f ? t0 : expm1f(t0);
        float t1 = v.y + bs[4 * k4 + 1]; r[4 * k4 + 1] = t1 > 0.f ? t1 : expm1f(t1);
        float t2 = v.z + bs[4 * k4 + 2]; r[4 * k4 + 2] = t2 > 0.f ? t2 : expm1f(t2);
        float t3 = v.w + bs[4 * k4 + 3]; r[4 * k4 + 3] = t3 > 0.f ? t3 : expm1f(t3);
    }
    float m = r[0];
    #pragma unroll
    for (int j = 1; j < NCLS; ++j) m = fmaxf(m, r[j]);
    float s = 0.f;
    #pragma unroll
    for (int j = 0; j < NCLS; ++j) s += expf(r[j] - m);
    float lse = logf(s) + m;
    float4* o = (float4*)(out + (size_t)n * NCLS);
    #pragma unroll
    for (int j4 = 0; j4 < NCLS / 4; ++j4)
        o[j4] = make_float4(r[4 * j4] - lse, r[4 * j4 + 1] - lse,
                            r[4 * j4 + 2] - lse, r[4 * j4 + 3] - lse);
}

extern "C" void kernel_launch(void* const* d_in, const int* in_sizes, int n_in,
                              void* d_out, int out_size, void* d_ws, size_t ws_size,
                              hipStream_t stream) {
    const float* x  = (const float*)d_in[0];
    const int*   ei = (const int*)d_in[1];
    const float* W1 = (const float*)d_in[2];
    const float* b1 = (const float*)d_in[3];
    const float* W2 = (const float*)d_in[4];
    const float* b2 = (const float*)d_in[5];
    const float* W3 = (const float*)d_in[6];
    const float* b3 = (const float*)d_in[7];
    float* out = (float*)d_out;
    const int* src = ei;
    const int* dst = ei + N_EDGES;

    float* ws  = (float*)d_ws;
    float* dis = ws;                  // 102400 (N rounded up)
    float* nrm = dis + 102400;        // E
    float* B   = nrm + N_EDGES;       // N*16 rounded to 1638400
    float* C   = B + 1638400;         // N*16
    float* H3  = C + 1638400;         // N*32 rounded to 3276800
    float* A3  = H3 + 3276800;        // N*32

    auto blocks = [](long long n) { return (int)((n + 255) / 256); };

    k_init_deg<<<blocks(N_NODES), 256, 0, stream>>>(dis);
    k_count_deg<<<blocks(N_EDGES), 256, 0, stream>>>(dst, dis);
    k_rsqrt<<<blocks(N_NODES), 256, 0, stream>>>(dis);
    k_norm<<<blocks(N_EDGES), 256, 0, stream>>>(src, dst, dis, nrm);

    // Layer 1: 256 -> 16
    k_linear1<<<blocks(N_NODES), 256, 0, stream>>>(x, W1, B);
    k_init_agg<16><<<blocks((long long)N_NODES * 16), 256, 0, stream>>>(B, dis, C);
    k_scatter<16><<<blocks((long long)N_EDGES * 16), 256, 0, stream>>>(src, dst, nrm, B, C);
    k_finlin<16, 16><<<blocks(N_NODES), 256, 0, stream>>>(C, b1, W2, B);

    // Layer 2: 16 -> 16 (linear already fused above; B holds h2 = elu(agg1+b1)@W2)
    k_init_agg<16><<<blocks((long long)N_NODES * 16), 256, 0, stream>>>(B, dis, C);
    k_scatter<16><<<blocks((long long)N_EDGES * 16), 256, 0, stream>>>(src, dst, nrm, B, C);
    k_finlin<16, 32><<<blocks(N_NODES), 256, 0, stream>>>(C, b2, W3, H3);

    // Layer 3: aggregation on 32-wide features, then bias+elu+log_softmax
    k_init_agg<32><<<blocks((long long)N_NODES * 32), 256, 0, stream>>>(H3, dis, A3);
    k_scatter<32><<<blocks((long long)N_EDGES * 32), 256, 0, stream>>>(src, dst, nrm, H3, A3);
    k_final<<<blocks(N_NODES), 256, 0, stream>>>(A3, b3, out);
}

// Round 2
// 655.756 us; speedup vs baseline: 1.4460x; 1.4460x over previous
//
#include <hip/hip_runtime.h>
#include <math.h>

static constexpr int N_NODES = 100000;
static constexpr int N_EDGES = 3200000;
static constexpr int F_INC   = 256;
static constexpr int HIDC    = 16;
static constexpr int NCLS    = 32;

// ---------------- CSR build ----------------

__global__ void k_zero(int* cnt, int* cursor) {
    int i = blockIdx.x * blockDim.x + threadIdx.x;
    if (i < 102400) cnt[i] = 0;
    if (i == 0) *cursor = 0;
}

__global__ void k_count(const int* __restrict__ dst, int* cnt) {
    int e = blockIdx.x * blockDim.x + threadIdx.x;
    if (e < N_EDGES) atomicAdd(&cnt[dst[e]], 1);
}

__global__ void k_alloc(const int* __restrict__ cnt, int* cursor,
                        int* __restrict__ rowptr, int* __restrict__ fillpos,
                        float* __restrict__ dis) {
    int i = blockIdx.x * blockDim.x + threadIdx.x;
    if (i >= N_NODES) return;
    int c = cnt[i];
    int pos = atomicAdd(cursor, c);
    rowptr[i] = pos;
    fillpos[i] = pos;
    dis[i] = rsqrtf((float)c + 1.0f);
}

__global__ void k_fill(const int* __restrict__ src, const int* __restrict__ dst,
                       int* fillpos, int* __restrict__ csr_src) {
    int e = blockIdx.x * blockDim.x + threadIdx.x;
    if (e >= N_EDGES) return;
    int t = dst[e];
    int p = atomicAdd(&fillpos[t], 1);
    csr_src[p] = src[e];
}

// ---------------- dense kernels ----------------

__global__ __launch_bounds__(256) void k_linear1(const float* __restrict__ x,
                                                 const float* __restrict__ W1,
                                                 float* __restrict__ h) {
    __shared__ float Ws[F_INC * HIDC];
    for (int i = threadIdx.x; i < F_INC * HIDC; i += 256) Ws[i] = W1[i];
    __syncthreads();
    int n = blockIdx.x * blockDim.x + threadIdx.x;
    if (n >= N_NODES) return;
    float acc[HIDC];
    #pragma unroll
    for (int j = 0; j < HIDC; ++j) acc[j] = 0.f;
    const float4* xr = (const float4*)(x + (size_t)n * F_INC);
    for (int k4 = 0; k4 < F_INC / 4; ++k4) {
        float4 v = xr[k4];
        const float* w = &Ws[k4 * 4 * HIDC];
        #pragma unroll
        for (int j = 0; j < HIDC; ++j)
            acc[j] += v.x * w[j] + v.y * w[HIDC + j] + v.z * w[2 * HIDC + j] + v.w * w[3 * HIDC + j];
    }
    float4* o = (float4*)(h + (size_t)n * HIDC);
    #pragma unroll
    for (int j4 = 0; j4 < HIDC / 4; ++j4)
        o[j4] = make_float4(acc[4 * j4], acc[4 * j4 + 1], acc[4 * j4 + 2], acc[4 * j4 + 3]);
}

// gather aggregation: agg[n,d] = dis[n] * (dis[n]*h[n,d] + sum_{s in in(n)} dis[s]*h[s,d])
template<int D>
__global__ __launch_bounds__(256) void k_gather(const int* __restrict__ rowptr,
                                                const int* __restrict__ cnt,
                                                const int* __restrict__ csr_src,
                                                const float* __restrict__ dis,
                                                const float* __restrict__ h,
                                                float* __restrict__ agg) {
    int idx = blockIdx.x * blockDim.x + threadIdx.x;
    int n = idx / D;
    int d = idx - n * D;
    if (n >= N_NODES) return;
    float dn = dis[n];
    int base = rowptr[n];
    int deg = cnt[n];
    float acc = dn * h[(size_t)n * D + d];
    int j = 0;
    for (; j + 3 < deg; j += 4) {
        int s0 = csr_src[base + j];
        int s1 = csr_src[base + j + 1];
        int s2 = csr_src[base + j + 2];
        int s3 = csr_src[base + j + 3];
        float v0 = dis[s0] * h[(size_t)s0 * D + d];
        float v1 = dis[s1] * h[(size_t)s1 * D + d];
        float v2 = dis[s2] * h[(size_t)s2 * D + d];
        float v3 = dis[s3] * h[(size_t)s3 * D + d];
        acc += (v0 + v1) + (v2 + v3);
    }
    for (; j < deg; ++j) {
        int s = csr_src[base + j];
        acc += dis[s] * h[(size_t)s * D + d];
    }
    agg[idx] = dn * acc;
}

// layer-3 gather fused with bias + ELU + log_softmax (32-lane groups)
__global__ __launch_bounds__(256) void k_gather32_final(const int* __restrict__ rowptr,
                                                        const int* __restrict__ cnt,
                                                        const int* __restrict__ csr_src,
                                                        const float* __restrict__ dis,
                                                        const float* __restrict__ h,
                                                        const float* __restrict__ bias,
                                                        float* __restrict__ out) {
    int idx = blockIdx.x * blockDim.x + threadIdx.x;
    int n = idx / NCLS;
    int d = idx - n * NCLS;
    if (n >= N_NODES) return;
    float dn = dis[n];
    int base = rowptr[n];
    int deg = cnt[n];
    float acc = dn * h[(size_t)n * NCLS + d];
    int j = 0;
    for (; j + 3 < deg; j += 4) {
        int s0 = csr_src[base + j];
        int s1 = csr_src[base + j + 1];
        int s2 = csr_src[base + j + 2];
        int s3 = csr_src[base + j + 3];
        float v0 = dis[s0] * h[(size_t)s0 * NCLS + d];
        float v1 = dis[s1] * h[(size_t)s1 * NCLS + d];
        float v2 = dis[s2] * h[(size_t)s2 * NCLS + d];
        float v3 = dis[s3] * h[(size_t)s3 * NCLS + d];
        acc += (v0 + v1) + (v2 + v3);
    }
    for (; j < deg; ++j) {
        int s = csr_src[base + j];
        acc += dis[s] * h[(size_t)s * NCLS + d];
    }
    float r = dn * acc + bias[d];
    r = r > 0.f ? r : expm1f(r);
    // log_softmax across the 32 lanes of this node (width-32 shuffle groups)
    float m = r;
    #pragma unroll
    for (int off = 16; off > 0; off >>= 1) m = fmaxf(m, __shfl_xor(m, off, 32));
    float s = expf(r - m);
    #pragma unroll
    for (int off = 16; off > 0; off >>= 1) s += __shfl_xor(s, off, 32);
    out[idx] = r - (logf(s) + m);
}

template<int DIN, int DOUT>
__global__ __launch_bounds__(256) void k_finlin(const float* __restrict__ agg,
                                                const float* __restrict__ bias,
                                                const float* __restrict__ W,
                                                float* __restrict__ hout) {
    __shared__ float Ws[DIN * DOUT];
    __shared__ float bs[DIN];
    for (int i = threadIdx.x; i < DIN * DOUT; i += 256) Ws[i] = W[i];
    if (threadIdx.x < DIN) bs[threadIdx.x] = bias[threadIdx.x];
    __syncthreads();
    int n = blockIdx.x * blockDim.x + threadIdx.x;
    if (n >= N_NODES) return;
    float act[DIN];
    const float4* ar = (const float4*)(agg + (size_t)n * DIN);
    #pragma unroll
    for (int k4 = 0; k4 < DIN / 4; ++k4) {
        float4 v = ar[k4];
        float t0 = v.x + bs[4 * k4 + 0]; act[4 * k4 + 0] = t0 > 0.f ? t0 : expm1f(t0);
        float t1 = v.y + bs[4 * k4 + 1]; act[4 * k4 + 1] = t1 > 0.f ? t1 : expm1f(t1);
        float t2 = v.z + bs[4 * k4 + 2]; act[4 * k4 + 2] = t2 > 0.f ? t2 : expm1f(t2);
        float t3 = v.w + bs[4 * k4 + 3]; act[4 * k4 + 3] = t3 > 0.f ? t3 : expm1f(t3);
    }
    float acc[DOUT];
    #pragma unroll
    for (int j = 0; j < DOUT; ++j) acc[j] = 0.f;
    for (int k = 0; k < DIN; ++k) {
        float a = act[k];
        #pragma unroll
        for (int j = 0; j < DOUT; ++j) acc[j] += a * Ws[k * DOUT + j];
    }
    float4* o = (float4*)(hout + (size_t)n * DOUT);
    #pragma unroll
    for (int j4 = 0; j4 < DOUT / 4; ++j4)
        o[j4] = make_float4(acc[4 * j4], acc[4 * j4 + 1], acc[4 * j4 + 2], acc[4 * j4 + 3]);
}

extern "C" void kernel_launch(void* const* d_in, const int* in_sizes, int n_in,
                              void* d_out, int out_size, void* d_ws, size_t ws_size,
                              hipStream_t stream) {
    const float* x  = (const float*)d_in[0];
    const int*   ei = (const int*)d_in[1];
    const float* W1 = (const float*)d_in[2];
    const float* b1 = (const float*)d_in[3];
    const float* W2 = (const float*)d_in[4];
    const float* b2 = (const float*)d_in[5];
    const float* W3 = (const float*)d_in[6];
    const float* b3 = (const float*)d_in[7];
    float* out = (float*)d_out;
    const int* src = ei;
    const int* dst = ei + N_EDGES;

    // workspace layout (all 4-byte elements)
    int*   wi      = (int*)d_ws;
    int*   cnt     = wi;                  // 102400
    int*   rowptr  = wi + 102400;         // 102400
    int*   fillpos = wi + 204800;         // 102400
    int*   cursor  = wi + 307200;         // 1 (+pad to 307456)
    int*   csr_src = wi + 307456;         // 3200000 -> ends 3507456
    float* wf      = (float*)d_ws;
    float* dis     = wf + 3507456;        // 102400
    float* B       = wf + 3609856;        // 1638400 (N*16)
    float* C       = wf + 5248256;        // 1638400
    float* H3      = wf + 6886656;        // 3276800 (N*32)

    auto blocks = [](long long n) { return (int)((n + 255) / 256); };

    // CSR build (bucket order is arbitrary; sum is order-insensitive within fp tolerance)
    k_zero<<<blocks(102400), 256, 0, stream>>>(cnt, cursor);
    k_count<<<blocks(N_EDGES), 256, 0, stream>>>(dst, cnt);
    k_alloc<<<blocks(N_NODES), 256, 0, stream>>>(cnt, cursor, rowptr, fillpos, dis);
    k_fill<<<blocks(N_EDGES), 256, 0, stream>>>(src, dst, fillpos, csr_src);

    // Layer 1: x @ W1 -> gather -> (bias+ELU) @ W2
    k_linear1<<<blocks(N_NODES), 256, 0, stream>>>(x, W1, B);
    k_gather<16><<<blocks((long long)N_NODES * 16), 256, 0, stream>>>(rowptr, cnt, csr_src, dis, B, C);
    k_finlin<16, 16><<<blocks(N_NODES), 256, 0, stream>>>(C, b1, W2, B);

    // Layer 2: gather -> (bias+ELU) @ W3
    k_gather<16><<<blocks((long long)N_NODES * 16), 256, 0, stream>>>(rowptr, cnt, csr_src, dis, B, C);
    k_finlin<16, 32><<<blocks(N_NODES), 256, 0, stream>>>(C, b2, W3, H3);

    // Layer 3: gather fused with bias + ELU + log_softmax
    k_gather32_final<<<blocks((long long)N_NODES * 32), 256, 0, stream>>>(rowptr, cnt, csr_src, dis, H3, b3, out);
}